// Round 1
// baseline (294.679 us; speedup 1.0000x reference)
//
#include <hip/hip_runtime.h>
#include <hip/hip_bf16.h>

typedef __bf16 bf16;
typedef __bf16 bf16x8 __attribute__((ext_vector_type(8)));
typedef __bf16 bf16x4 __attribute__((ext_vector_type(4)));
typedef float f32x4 __attribute__((ext_vector_type(4)));

#define B_   4
#define T_   2048
#define DM_  1024
#define DH_  1024
#define MROWS (B_ * T_)   // 8192 rows for all GEMMs

// ---------------------------------------------------------------------------
// fp32 -> bf16 conversion, 8 elems/thread, batched over 7 tensors via grid.y
// ---------------------------------------------------------------------------
struct CvtJob { const float* src; bf16* dst; int n; };
struct CvtArgs { CvtJob job[7]; };

__global__ __launch_bounds__(256) void cvt_kernel(CvtArgs args) {
  CvtJob jb = args.job[blockIdx.y];
  int i = (blockIdx.x * 256 + threadIdx.x) * 8;
  if (i >= jb.n) return;
  const float4* s = (const float4*)(jb.src + i);
  float4 a = s[0];
  float4 b = s[1];
  bf16x8 o;
  o[0] = (bf16)a.x; o[1] = (bf16)a.y; o[2] = (bf16)a.z; o[3] = (bf16)a.w;
  o[4] = (bf16)b.x; o[5] = (bf16)b.y; o[6] = (bf16)b.z; o[7] = (bf16)b.w;
  *(bf16x8*)(jb.dst + i) = o;
}

// ---------------------------------------------------------------------------
// C[M,N] (fp32) = A[M,K] (bf16) * B[N,K]^T (bf16); all row-major, K-fast.
// m97 structure: 128x128 tile, BK=64, 4 waves in 2x2, each wave 4x4 MFMA
// 16x16x32 tiles. global_load_lds width=16, XOR-swizzled LDS (no padding
// allowed: LDS dst is wave-uniform base + lane*16).
// M,N,K all multiples of 128/64 here -> no bounds checks.
// ---------------------------------------------------------------------------
__global__ __launch_bounds__(256) void gemm_bt(
    const bf16* __restrict__ A, const bf16* __restrict__ B,
    float* __restrict__ C, int M, int N, int K) {
  __shared__ bf16 As[128 * 64];   // [row 0..127][k 0..63], 16 KB
  __shared__ bf16 Bs[128 * 64];

  const int tid  = threadIdx.x;
  const int lane = tid & 63;
  const int wave = tid >> 6;            // 0..3
  const int wm   = (wave >> 1) * 64;    // wave row offset in tile
  const int wn   = (wave & 1) * 64;    // wave col offset in tile
  const int tileM = blockIdx.y * 128;
  const int tileN = blockIdx.x * 128;

  f32x4 acc[4][4] = {};                 // [mt][nt], 64 fp32/lane

  // staging: lane covers LDS row (grp*8 + lane/8), physical chunk (lane%8);
  // source k-chunk is XOR-swizzled so reads can de-swizzle by row.
  const int sr = lane >> 3;             // 0..7
  const int sc = (lane & 7) ^ sr;       // swizzled source chunk 0..7

  for (int k0 = 0; k0 < K; k0 += 64) {
#pragma unroll
    for (int l = 0; l < 4; ++l) {
      int grp = wave * 4 + l;           // 0..15 -> rows [grp*8, grp*8+8)
      int row = grp * 8 + sr;
      const bf16* ga = A + (size_t)(tileM + row) * K + k0 + sc * 8;
      __builtin_amdgcn_global_load_lds(
          (const __attribute__((address_space(1))) void*)ga,
          (__attribute__((address_space(3))) void*)&As[grp * 512], 16, 0, 0);
      const bf16* gb = B + (size_t)(tileN + row) * K + k0 + sc * 8;
      __builtin_amdgcn_global_load_lds(
          (const __attribute__((address_space(1))) void*)gb,
          (__attribute__((address_space(3))) void*)&Bs[grp * 512], 16, 0, 0);
    }
    __syncthreads();

    const int quad = lane >> 4;
#pragma unroll
    for (int s = 0; s < 2; ++s) {       // two K=32 sub-steps of BK=64
      bf16x8 af[4], bfr[4];
#pragma unroll
      for (int mt = 0; mt < 4; ++mt) {
        int row = wm + mt * 16 + (lane & 15);
        int chunk = (s * 4 + quad) ^ (row & 7);   // de-swizzle
        af[mt] = *(const bf16x8*)&As[row * 64 + chunk * 8];
      }
#pragma unroll
      for (int nt = 0; nt < 4; ++nt) {
        int row = wn + nt * 16 + (lane & 15);
        int chunk = (s * 4 + quad) ^ (row & 7);
        bfr[nt] = *(const bf16x8*)&Bs[row * 64 + chunk * 8];
      }
#pragma unroll
      for (int mt = 0; mt < 4; ++mt)
#pragma unroll
        for (int nt = 0; nt < 4; ++nt)
          acc[mt][nt] = __builtin_amdgcn_mfma_f32_16x16x32_bf16(
              af[mt], bfr[nt], acc[mt][nt], 0, 0, 0);
    }
    __syncthreads();
  }

  // epilogue: C/D layout col=lane&15, row=(lane>>4)*4+reg (m89/m91 verified)
  const int cn = lane & 15;
  const int cr = (lane >> 4) * 4;
#pragma unroll
  for (int mt = 0; mt < 4; ++mt)
#pragma unroll
    for (int nt = 0; nt < 4; ++nt)
#pragma unroll
      for (int r = 0; r < 4; ++r) {
        int row = tileM + wm + mt * 16 + cr + r;
        int col = tileN + wn + nt * 16 + cn;
        C[(size_t)row * N + col] = acc[mt][nt][r];
      }
}

// ---------------------------------------------------------------------------
// ratio reduction: m[j,d]=max_b K[b,j,d]; w=exp(K-m);
// num[b,d]+=w*V; den[b,d]+=w  (atomics over 64 j-splits)
// ---------------------------------------------------------------------------
__global__ __launch_bounds__(256) void reduce_kv(
    const float* __restrict__ Kf, const float* __restrict__ Vf,
    float* __restrict__ num, float* __restrict__ den) {
  const int d  = blockIdx.x * 256 + threadIdx.x;   // gridDim.x = 4 -> d 0..1023
  const int j0 = blockIdx.y * 32;                  // gridDim.y = 64
  const size_t bs = (size_t)T_ * DH_;
  float n0 = 0, n1 = 0, n2 = 0, n3 = 0, e0 = 0, e1 = 0, e2 = 0, e3 = 0;
#pragma unroll 2
  for (int j = j0; j < j0 + 32; ++j) {
    size_t off = (size_t)j * DH_ + d;
    float k0 = Kf[off], k1 = Kf[off + bs], k2 = Kf[off + 2 * bs], k3 = Kf[off + 3 * bs];
    float v0 = Vf[off], v1 = Vf[off + bs], v2 = Vf[off + 2 * bs], v3 = Vf[off + 3 * bs];
    float m = fmaxf(fmaxf(k0, k1), fmaxf(k2, k3));
    float w0 = __expf(k0 - m), w1 = __expf(k1 - m);
    float w2 = __expf(k2 - m), w3 = __expf(k3 - m);
    e0 += w0; e1 += w1; e2 += w2; e3 += w3;
    n0 += w0 * v0; n1 += w1 * v1; n2 += w2 * v2; n3 += w3 * v3;
  }
  atomicAdd(&num[0 * DH_ + d], n0);
  atomicAdd(&num[1 * DH_ + d], n1);
  atomicAdd(&num[2 * DH_ + d], n2);
  atomicAdd(&num[3 * DH_ + d], n3);
  atomicAdd(&den[0 * DH_ + d], e0);
  atomicAdd(&den[1 * DH_ + d], e1);
  atomicAdd(&den[2 * DH_ + d], e2);
  atomicAdd(&den[3 * DH_ + d], e3);
}

// ---------------------------------------------------------------------------
// Y[b,t,h] = sigmoid(Q[b,t,h]) * num[b,h]/den[b,h]  -> bf16 (GEMM2 A operand)
// ---------------------------------------------------------------------------
__global__ __launch_bounds__(256) void make_y(
    const float* __restrict__ Qf, const float* __restrict__ num,
    const float* __restrict__ den, bf16* __restrict__ Yb) {
  size_t i = ((size_t)blockIdx.x * 256 + threadIdx.x) * 4;  // grid = 8192
  int h = (int)(i & (DH_ - 1));
  int b = (int)(i >> 21);                 // i / (T_*DH_) ; 2048*1024 = 2^21
  float4 qv = *(const float4*)(Qf + i);
  float r0 = num[b * DH_ + h + 0] / den[b * DH_ + h + 0];
  float r1 = num[b * DH_ + h + 1] / den[b * DH_ + h + 1];
  float r2 = num[b * DH_ + h + 2] / den[b * DH_ + h + 2];
  float r3 = num[b * DH_ + h + 3] / den[b * DH_ + h + 3];
  bf16x4 y;
  y[0] = (bf16)(r0 / (1.f + __expf(-qv.x)));
  y[1] = (bf16)(r1 / (1.f + __expf(-qv.y)));
  y[2] = (bf16)(r2 / (1.f + __expf(-qv.z)));
  y[3] = (bf16)(r3 / (1.f + __expf(-qv.w)));
  *(bf16x4*)(Yb + i) = y;
}

// ---------------------------------------------------------------------------
extern "C" void kernel_launch(void* const* d_in, const int* in_sizes, int n_in,
                              void* d_out, int out_size, void* d_ws, size_t ws_size,
                              hipStream_t stream) {
  const float* q  = (const float*)d_in[0];
  const float* k  = (const float*)d_in[1];
  const float* v  = (const float*)d_in[2];
  const float* Wq = (const float*)d_in[3];
  const float* Wk = (const float*)d_in[4];
  const float* Wv = (const float*)d_in[5];
  const float* Wo = (const float*)d_in[6];
  // d_in[7] = W_bias is mathematically unused: exp(pos_bias - max(pos_bias,
  // axis=0 over a singleton dim)) == all-ones, so both T×T einsums collapse
  // to sums over j.
  float* out = (float*)d_out;

  char* ws = (char*)d_ws;
  size_t off = 0;
  auto alloc = [&](size_t bytes) {
    char* p = ws + off;
    off += (bytes + 255) & ~(size_t)255;
    return p;
  };
  const size_t actN = (size_t)MROWS * DM_;   // 8388608
  const size_t wN   = (size_t)DH_ * DM_;     // 1048576

  bf16* qb  = (bf16*)alloc(actN * 2);
  bf16* kb  = (bf16*)alloc(actN * 2);
  bf16* vb  = (bf16*)alloc(actN * 2);
  bf16* Wqb = (bf16*)alloc(wN * 2);
  bf16* Wkb = (bf16*)alloc(wN * 2);
  bf16* Wvb = (bf16*)alloc(wN * 2);
  bf16* Wob = (bf16*)alloc(wN * 2);
  float* Qf = (float*)alloc(actN * 4);
  float* Kf = (float*)alloc(actN * 4);
  float* Vf = (float*)alloc(actN * 4);
  float* num = (float*)alloc(B_ * DH_ * 4);
  float* den = (float*)alloc(B_ * DH_ * 4);
  bf16* Yb = qb;   // qb is dead after GEMM-Q; reuse for Y

  // 1) convert everything to bf16 (one launch, 7 jobs)
  CvtArgs ca;
  ca.job[0] = {q,  qb,  (int)actN};
  ca.job[1] = {k,  kb,  (int)actN};
  ca.job[2] = {v,  vb,  (int)actN};
  ca.job[3] = {Wq, Wqb, (int)wN};
  ca.job[4] = {Wk, Wkb, (int)wN};
  ca.job[5] = {Wv, Wvb, (int)wN};
  ca.job[6] = {Wo, Wob, (int)wN};
  cvt_kernel<<<dim3(actN / 8 / 256, 7), 256, 0, stream>>>(ca);

  dim3 ggrid(DH_ / 128, MROWS / 128);   // (8, 64)

  // 2) projections
  gemm_bt<<<ggrid, 256, 0, stream>>>(kb, Wkb, Kf, MROWS, DH_, DM_);
  gemm_bt<<<ggrid, 256, 0, stream>>>(vb, Wvb, Vf, MROWS, DH_, DM_);
  gemm_bt<<<ggrid, 256, 0, stream>>>(qb, Wqb, Qf, MROWS, DH_, DM_);

  // 3) batch-max + exp + sums  (num/den zero-init: ws is poisoned 0xAA)
  hipMemsetAsync(num, 0, 2 * B_ * DH_ * sizeof(float), stream);
  reduce_kv<<<dim3(4, 64), 256, 0, stream>>>(Kf, Vf, num, den);

  // 4) Y = sigmoid(Q) * num/den   (bf16, overwrites qb)
  make_y<<<dim3(actN / 4 / 256), 256, 0, stream>>>(Qf, num, den, Yb);

  // 5) output projection
  gemm_bt<<<ggrid, 256, 0, stream>>>(Yb, Wob, out, MROWS, DM_, DH_);
}

// Round 2
// 290.806 us; speedup vs baseline: 1.0133x; 1.0133x over previous
//
#include <hip/hip_runtime.h>
#include <hip/hip_bf16.h>

typedef __bf16 bf16;
typedef __bf16 bf16x8 __attribute__((ext_vector_type(8)));
typedef __bf16 bf16x4 __attribute__((ext_vector_type(4)));
typedef float f32x4 __attribute__((ext_vector_type(4)));

#define B_   4
#define T_   2048
#define DM_  1024
#define DH_  1024
#define MROWS (B_ * T_)   // 8192

// ---------------------------------------------------------------------------
// fp32 -> bf16, 16 elems/thread (4 independent dwordx4 loads in flight).
// Block covers 4096 elems = 1024 float4. Thread t: float4 idx {2t, 2t+1}
// (-> one bf16x8 store) and {2t+512, 2t+513} (-> second bf16x8 store).
// All n are multiples of 4096 so whole blocks predicate off uniformly.
// ---------------------------------------------------------------------------
struct CvtJob { const float* src; bf16* dst; int nf4; };  // nf4 = n/4
struct CvtArgs { CvtJob job[6]; };

__global__ __launch_bounds__(256) void cvt_kernel(CvtArgs args) {
  CvtJob jb = args.job[blockIdx.y];
  int f4 = blockIdx.x * 1024 + threadIdx.x * 2;
  if (f4 >= jb.nf4) return;
  const float4* s = (const float4*)jb.src;
  float4 a0 = s[f4];
  float4 a1 = s[f4 + 1];
  float4 b0 = s[f4 + 512];
  float4 b1 = s[f4 + 513];
  bf16x8 oa, ob;
  oa[0] = (bf16)a0.x; oa[1] = (bf16)a0.y; oa[2] = (bf16)a0.z; oa[3] = (bf16)a0.w;
  oa[4] = (bf16)a1.x; oa[5] = (bf16)a1.y; oa[6] = (bf16)a1.z; oa[7] = (bf16)a1.w;
  ob[0] = (bf16)b0.x; ob[1] = (bf16)b0.y; ob[2] = (bf16)b0.z; ob[3] = (bf16)b0.w;
  ob[4] = (bf16)b1.x; ob[5] = (bf16)b1.y; ob[6] = (bf16)b1.z; ob[7] = (bf16)b1.w;
  *(bf16x8*)(jb.dst + (size_t)f4 * 4) = oa;
  *(bf16x8*)(jb.dst + (size_t)(f4 + 512) * 4) = ob;
}

// ---------------------------------------------------------------------------
// C[M,N] = A[M,K] * B[N,K]^T, bf16 in, m97 structure (128x128 tile, BK=64,
// 4 waves 2x2, 4x4 MFMA 16x16x32, global_load_lds w=16, XOR-swizzled LDS).
// Multi-job via blockIdx.z: each job has its own A/B/C base. Epilogue:
// Cf != null -> fp32 store; else Cb -> bf16(sigmoid(acc)) store.
// ---------------------------------------------------------------------------
struct GemmJob { const bf16* A; const bf16* Bw; float* Cf; bf16* Cb; };
struct GemmArgs { GemmJob job[4]; int N; int K; };

__global__ __launch_bounds__(256) void gemm_bt(GemmArgs ga) {
  const GemmJob jb = ga.job[blockIdx.z];
  const int N = ga.N, K = ga.K;
  __shared__ bf16 As[128 * 64];
  __shared__ bf16 Bs[128 * 64];

  const int tid  = threadIdx.x;
  const int lane = tid & 63;
  const int wave = tid >> 6;
  const int wm   = (wave >> 1) * 64;
  const int wn   = (wave & 1) * 64;
  const int tileM = blockIdx.y * 128;
  const int tileN = blockIdx.x * 128;

  f32x4 acc[4][4] = {};

  const int sr = lane >> 3;
  const int sc = (lane & 7) ^ sr;

  for (int k0 = 0; k0 < K; k0 += 64) {
#pragma unroll
    for (int l = 0; l < 4; ++l) {
      int grp = wave * 4 + l;
      int row = grp * 8 + sr;
      const bf16* gaadr = jb.A + (size_t)(tileM + row) * K + k0 + sc * 8;
      __builtin_amdgcn_global_load_lds(
          (const __attribute__((address_space(1))) void*)gaadr,
          (__attribute__((address_space(3))) void*)&As[grp * 512], 16, 0, 0);
      const bf16* gbadr = jb.Bw + (size_t)(tileN + row) * K + k0 + sc * 8;
      __builtin_amdgcn_global_load_lds(
          (const __attribute__((address_space(1))) void*)gbadr,
          (__attribute__((address_space(3))) void*)&Bs[grp * 512], 16, 0, 0);
    }
    __syncthreads();

    const int quad = lane >> 4;
#pragma unroll
    for (int s = 0; s < 2; ++s) {
      bf16x8 af[4], bfr[4];
#pragma unroll
      for (int mt = 0; mt < 4; ++mt) {
        int row = wm + mt * 16 + (lane & 15);
        int chunk = (s * 4 + quad) ^ (row & 7);
        af[mt] = *(const bf16x8*)&As[row * 64 + chunk * 8];
      }
#pragma unroll
      for (int nt = 0; nt < 4; ++nt) {
        int row = wn + nt * 16 + (lane & 15);
        int chunk = (s * 4 + quad) ^ (row & 7);
        bfr[nt] = *(const bf16x8*)&Bs[row * 64 + chunk * 8];
      }
#pragma unroll
      for (int mt = 0; mt < 4; ++mt)
#pragma unroll
        for (int nt = 0; nt < 4; ++nt)
          acc[mt][nt] = __builtin_amdgcn_mfma_f32_16x16x32_bf16(
              af[mt], bfr[nt], acc[mt][nt], 0, 0, 0);
    }
    __syncthreads();
  }

  // epilogue: C/D layout col=lane&15, row=(lane>>4)*4+reg
  const int cn = lane & 15;
  const int cr = (lane >> 4) * 4;
  if (jb.Cf) {
#pragma unroll
    for (int mt = 0; mt < 4; ++mt)
#pragma unroll
      for (int nt = 0; nt < 4; ++nt)
#pragma unroll
        for (int r = 0; r < 4; ++r) {
          int row = tileM + wm + mt * 16 + cr + r;
          int col = tileN + wn + nt * 16 + cn;
          jb.Cf[(size_t)row * N + col] = acc[mt][nt][r];
        }
  } else {
#pragma unroll
    for (int mt = 0; mt < 4; ++mt)
#pragma unroll
      for (int nt = 0; nt < 4; ++nt)
#pragma unroll
        for (int r = 0; r < 4; ++r) {
          int row = tileM + wm + mt * 16 + cr + r;
          int col = tileN + wn + nt * 16 + cn;
          float sv = 1.f / (1.f + __expf(-acc[mt][nt][r]));
          jb.Cb[(size_t)row * N + col] = (bf16)sv;
        }
  }
}

// ---------------------------------------------------------------------------
// ratio reduction: m[j,d]=max_b K[b,j,d]; w=exp(K-m);
// num[b,d]+=w*V; den[b,d]+=w  (atomics over 64 j-splits)
// ---------------------------------------------------------------------------
__global__ __launch_bounds__(256) void reduce_kv(
    const float* __restrict__ Kf, const float* __restrict__ Vf,
    float* __restrict__ num, float* __restrict__ den) {
  const int d  = blockIdx.x * 256 + threadIdx.x;
  const int j0 = blockIdx.y * 32;
  const size_t bs = (size_t)T_ * DH_;
  float n0 = 0, n1 = 0, n2 = 0, n3 = 0, e0 = 0, e1 = 0, e2 = 0, e3 = 0;
#pragma unroll 2
  for (int j = j0; j < j0 + 32; ++j) {
    size_t off = (size_t)j * DH_ + d;
    float k0 = Kf[off], k1 = Kf[off + bs], k2 = Kf[off + 2 * bs], k3 = Kf[off + 3 * bs];
    float v0 = Vf[off], v1 = Vf[off + bs], v2 = Vf[off + 2 * bs], v3 = Vf[off + 3 * bs];
    float m = fmaxf(fmaxf(k0, k1), fmaxf(k2, k3));
    float w0 = __expf(k0 - m), w1 = __expf(k1 - m);
    float w2 = __expf(k2 - m), w3 = __expf(k3 - m);
    e0 += w0; e1 += w1; e2 += w2; e3 += w3;
    n0 += w0 * v0; n1 += w1 * v1; n2 += w2 * v2; n3 += w3 * v3;
  }
  atomicAdd(&num[0 * DH_ + d], n0);
  atomicAdd(&num[1 * DH_ + d], n1);
  atomicAdd(&num[2 * DH_ + d], n2);
  atomicAdd(&num[3 * DH_ + d], n3);
  atomicAdd(&den[0 * DH_ + d], e0);
  atomicAdd(&den[1 * DH_ + d], e1);
  atomicAdd(&den[2 * DH_ + d], e2);
  atomicAdd(&den[3 * DH_ + d], e3);
}

// ---------------------------------------------------------------------------
// Wos[b][m][h] = bf16( Wo[m][h] * num[b][h] / den[b][h] )  — folds the
// per-(b,h) ratio into 4 scaled copies of Wo, so the final GEMM's A operand
// is just sigmoid(Q) (written by the Q-GEMM epilogue, no reduce dependency).
// ---------------------------------------------------------------------------
__global__ __launch_bounds__(256) void scale_wo(
    const float* __restrict__ Wo, const float* __restrict__ num,
    const float* __restrict__ den, bf16* __restrict__ Wos) {
  int i = (blockIdx.x * 256 + threadIdx.x) * 4;   // grid 1024 -> 1M elems
  int h = i & (DH_ - 1);
  float4 w = *(const float4*)(Wo + i);
#pragma unroll
  for (int b = 0; b < 4; ++b) {
    float4 nu = *(const float4*)(num + b * DH_ + h);
    float4 de = *(const float4*)(den + b * DH_ + h);
    bf16x4 o;
    o[0] = (bf16)(w.x * nu.x / de.x);
    o[1] = (bf16)(w.y * nu.y / de.y);
    o[2] = (bf16)(w.z * nu.z / de.z);
    o[3] = (bf16)(w.w * nu.w / de.w);
    *(bf16x4*)(Wos + (size_t)b * DH_ * DM_ + i) = o;
  }
}

// ---------------------------------------------------------------------------
extern "C" void kernel_launch(void* const* d_in, const int* in_sizes, int n_in,
                              void* d_out, int out_size, void* d_ws, size_t ws_size,
                              hipStream_t stream) {
  const float* q  = (const float*)d_in[0];
  const float* k  = (const float*)d_in[1];
  const float* v  = (const float*)d_in[2];
  const float* Wq = (const float*)d_in[3];
  const float* Wk = (const float*)d_in[4];
  const float* Wv = (const float*)d_in[5];
  const float* Wo = (const float*)d_in[6];
  // d_in[7] = W_bias mathematically unused (exp_pos_bias == all-ones).
  float* out = (float*)d_out;

  char* ws = (char*)d_ws;
  size_t off = 0;
  auto alloc = [&](size_t bytes) {
    char* p = ws + off;
    off += (bytes + 255) & ~(size_t)255;
    return p;
  };
  const size_t actN = (size_t)MROWS * DM_;   // 8388608
  const size_t wN   = (size_t)DH_ * DM_;     // 1048576

  bf16* qb  = (bf16*)alloc(actN * 2);
  bf16* kb  = (bf16*)alloc(actN * 2);
  bf16* vb  = (bf16*)alloc(actN * 2);
  bf16* Wqb = (bf16*)alloc(wN * 2);
  bf16* Wkb = (bf16*)alloc(wN * 2);
  bf16* Wvb = (bf16*)alloc(wN * 2);
  float* Kf = (float*)alloc(actN * 4);
  float* Vf = (float*)alloc(actN * 4);
  bf16* Yb  = (bf16*)alloc(actN * 2);        // sigmoid(Q), bf16
  bf16* Wos = (bf16*)alloc(4 * wN * 2);      // 4 ratio-scaled Wo copies
  float* num = (float*)alloc(B_ * DH_ * 4);
  float* den = (float*)alloc(B_ * DH_ * 4);

  // 1) fp32 -> bf16 (q,k,v + Wq,Wk,Wv; Wo handled by scale_wo directly)
  CvtArgs ca;
  ca.job[0] = {q,  qb,  (int)(actN / 4)};
  ca.job[1] = {k,  kb,  (int)(actN / 4)};
  ca.job[2] = {v,  vb,  (int)(actN / 4)};
  ca.job[3] = {Wq, Wqb, (int)(wN / 4)};
  ca.job[4] = {Wk, Wkb, (int)(wN / 4)};
  ca.job[5] = {Wv, Wvb, (int)(wN / 4)};
  cvt_kernel<<<dim3(actN / 4 / 1024, 6), 256, 0, stream>>>(ca);

  hipMemsetAsync(num, 0, 2 * B_ * DH_ * sizeof(float), stream);

  // 2) merged K/V/Q projections (1536 blocks). Q-job epilogue writes
  //    bf16(sigmoid(acc)) straight to Yb.
  GemmArgs g1;
  g1.N = DH_; g1.K = DM_;
  g1.job[0] = {kb, Wkb, Kf, nullptr};
  g1.job[1] = {vb, Wvb, Vf, nullptr};
  g1.job[2] = {qb, Wqb, nullptr, Yb};
  g1.job[3] = {nullptr, nullptr, nullptr, nullptr};
  gemm_bt<<<dim3(DH_ / 128, MROWS / 128, 3), 256, 0, stream>>>(g1);

  // 3) batch-max + exp + sums
  reduce_kv<<<dim3(4, 64), 256, 0, stream>>>(Kf, Vf, num, den);

  // 4) fold ratio into Wo (4 scaled copies)
  scale_wo<<<dim3(wN / 4 / 256), 256, 0, stream>>>(Wo, num, den, Wos);

  // 5) out[b] = sigmoidQ[b] @ Wos[b]^T   (grid.z = b)
  GemmArgs g2;
  g2.N = DM_; g2.K = DH_;
  for (int b = 0; b < 4; ++b)
    g2.job[b] = {Yb + (size_t)b * T_ * DH_, Wos + (size_t)b * wN,
                 out + (size_t)b * T_ * DM_, nullptr};
  gemm_bt<<<dim3(DM_ / 128, T_ / 128, 4), 256, 0, stream>>>(g2);
}